// Round 14
// baseline (34.006 us; speedup 1.0000x reference)
//
#include <hip/hip_runtime.h>
#include <math.h>

typedef __attribute__((ext_vector_type(8))) short short8;   // 8 bf16 vals
typedef __attribute__((ext_vector_type(4))) float f32x4;

// Problem constants (fixed by the reference)
constexpr int B = 8192;
constexpr int D = 128;
constexpr int K = 256;
constexpr int RB = K / 16;      // 16 reg-blocks (C.C^T tiles), run first
constexpr int HB = B / 16;      // 512 h-blocks
constexpr int GRID = RB + HB;   // 528

// ws layout (floats):
//   ctr          : [0]        (unsigned, zeroed by in-graph memset each call)
//   part_reg_sum : [16, 32)
//   part_loss    : [64, 576)

__device__ __forceinline__ short8 cvt8(float4 f0, float4 f1, float& sq) {
  sq = fmaf(f0.x, f0.x, fmaf(f0.y, f0.y, fmaf(f0.z, f0.z, fmaf(f0.w, f0.w, sq))));
  sq = fmaf(f1.x, f1.x, fmaf(f1.y, f1.y, fmaf(f1.z, f1.z, fmaf(f1.w, f1.w, sq))));
  union { short8 s; __bf16 b[8]; } u;
  u.b[0] = (__bf16)f0.x; u.b[1] = (__bf16)f0.y;
  u.b[2] = (__bf16)f0.z; u.b[3] = (__bf16)f0.w;
  u.b[4] = (__bf16)f1.x; u.b[5] = (__bf16)f1.y;
  u.b[6] = (__bf16)f1.z; u.b[7] = (__bf16)f1.w;
  return u.s;
}

// --- Single fused kernel ----------------------------------------------------
// Blocks [0,16): reg tiles — A = centers rows, epilogue = min/−log/sum.
// Blocks [16,528): h tiles — A = h rows, epilogue = exp-sum/logsumexp/y-gather.
// A and B both loaded fp32 (L2-hot for B), converted to bf16 in-register;
// exact fp32 row/col norms via shfl (+bpermute for rows).
// C-map (m89, rounds 6/10/11-verified): col = lane&15, row = (lane>>4)*4+reg.
// Last block to finish (atomic counter) performs the final scalar reduction.
__global__ __launch_bounds__(256) void main_kernel(
    const float* __restrict__ h, const int* __restrict__ y,
    const float* __restrict__ centers,
    unsigned* ctr, float* part_loss, float* part_reg_sum,
    float* out) {
  const int t = threadIdx.x;
  const int w = t >> 6;
  const int l = t & 63;
  const int lr = l & 15;
  const int lg = l >> 4;
  const bool isreg = (blockIdx.x < RB);
  const int r0 = (isreg ? (int)blockIdx.x : (int)blockIdx.x - RB) * 16;
  const float* Ap = (isreg ? centers : h) + (size_t)(r0 + lr) * D + lg * 8;
  const int n0 = w * 64;

  // ---- A fragments + exact fp32 row norms ----
  short8 a[4];
  float sq = 0.f;
#pragma unroll
  for (int c = 0; c < 4; ++c) {
    const float4* p = reinterpret_cast<const float4*>(Ap + c * 32);
    a[c] = cvt8(p[0], p[1], sq);
  }
  sq += __shfl_xor(sq, 16);
  sq += __shfl_xor(sq, 32);
  float rr[4];  // row norm of rows r0 + lg*4 + j
#pragma unroll
  for (int j = 0; j < 4; ++j)
    rr[j] = __int_as_float(
        __builtin_amdgcn_ds_bpermute((lg * 4 + j) << 2, __float_as_int(sq)));

  // ---- B stream: fp32 load -> bf16 frag -> MFMA; fp32 col norms ----
  f32x4 zero = {0.f, 0.f, 0.f, 0.f};
  f32x4 acc[4] = {zero, zero, zero, zero};
  float cs[4] = {0.f, 0.f, 0.f, 0.f};
#pragma unroll
  for (int c = 0; c < 4; ++c) {
#pragma unroll
    for (int n = 0; n < 4; ++n) {
      const float4* p = reinterpret_cast<const float4*>(
          centers + (size_t)(n0 + n * 16 + lr) * D + c * 32 + lg * 8);
      short8 bfrag = cvt8(p[0], p[1], cs[n]);
      acc[n] = __builtin_amdgcn_mfma_f32_16x16x32_bf16(a[c], bfrag, acc[n], 0, 0, 0);
    }
  }
#pragma unroll
  for (int n = 0; n < 4; ++n) {
    cs[n] += __shfl_xor(cs[n], 16);
    cs[n] += __shfl_xor(cs[n], 32);
  }

  __shared__ float ls[4][16];
  __shared__ float ldy[4][16];
  __shared__ int s_last;

  if (!isreg) {
    int y_r[4];
#pragma unroll
    for (int j = 0; j < 4; ++j) y_r[j] = y[r0 + lg * 4 + j];
    float s[4] = {0.f, 0.f, 0.f, 0.f}, dyv[4] = {0.f, 0.f, 0.f, 0.f};
#pragma unroll
    for (int n = 0; n < 4; ++n) {
      const int colg = n0 + n * 16 + lr;
      const float ccv = cs[n];
#pragma unroll
      for (int j = 0; j < 4; ++j) {
        float dist = fmaxf(fmaf(-2.f, acc[n][j], rr[j] + ccv), 0.f);
        if (y_r[j] == colg) dyv[j] = dist;
        s[j] += __expf(-sqrtf(dist));
      }
    }
#pragma unroll
    for (int j = 0; j < 4; ++j) {
#pragma unroll
      for (int off = 1; off < 16; off <<= 1) {
        s[j]   += __shfl_xor(s[j], off);
        dyv[j] += __shfl_xor(dyv[j], off);
      }
    }
    if (lr == 0) {
#pragma unroll
      for (int j = 0; j < 4; ++j) {
        ls[w][lg * 4 + j]  = s[j];
        ldy[w][lg * 4 + j] = dyv[j];
      }
    }
    __syncthreads();
    if (t < 16) {
      float stot = (ls[0][t] + ls[1][t]) + (ls[2][t] + ls[3][t]);
      float dtot = (ldy[0][t] + ldy[1][t]) + (ldy[2][t] + ldy[3][t]);
      float v = dtot + logf(fmaxf(stot, 1e-37f));
#pragma unroll
      for (int off = 1; off < 16; off <<= 1) v += __shfl_xor(v, off);
      if (t == 0) part_loss[blockIdx.x - RB] = v;
    }
  } else {
    float pmin[4] = {INFINITY, INFINITY, INFINITY, INFINITY};
#pragma unroll
    for (int n = 0; n < 4; ++n) {
      const int colg = n0 + n * 16 + lr;
      const float ccv = cs[n];
#pragma unroll
      for (int j = 0; j < 4; ++j) {
        const int irow = r0 + lg * 4 + j;
        float pd = fmaf(-2.f, acc[n][j], rr[j] + ccv);
        if (colg != irow) pmin[j] = fminf(pmin[j], pd);
      }
    }
#pragma unroll
    for (int j = 0; j < 4; ++j) {
#pragma unroll
      for (int off = 1; off < 16; off <<= 1)
        pmin[j] = fminf(pmin[j], __shfl_xor(pmin[j], off));
    }
    if (lr == 0) {
#pragma unroll
      for (int j = 0; j < 4; ++j) ls[w][lg * 4 + j] = pmin[j];
    }
    __syncthreads();
    if (t < 16) {
      float m = fminf(fminf(ls[0][t], ls[1][t]), fminf(ls[2][t], ls[3][t]));
      float v = -logf(fmaxf(m, 1e-37f));
#pragma unroll
      for (int off = 1; off < 16; off <<= 1) v += __shfl_xor(v, off);
      if (t == 0) part_reg_sum[blockIdx.x] = v;
    }
  }

  // ---- last-block-done final reduction ----
  if (t == 0) {
    __threadfence();                       // release: partial visible device-wide
    unsigned old = atomicAdd(ctr, 1u);     // device-scope RMW (m20)
    s_last = (old == (unsigned)(GRID - 1));
  }
  __syncthreads();
  if (s_last) {
    __threadfence();                       // acquire: see all partials
    float v = (part_loss[t] + part_loss[t + 256]) * (1.0f / (float)B);
    if (t < RB) v += part_reg_sum[t];
#pragma unroll
    for (int off = 32; off; off >>= 1) v += __shfl_xor(v, off);
    __shared__ float red[4];
    if (l == 0) red[w] = v;
    __syncthreads();
    if (t == 0) out[0] = (red[0] + red[1]) + (red[2] + red[3]);
  }
}

extern "C" void kernel_launch(void* const* d_in, const int* in_sizes, int n_in,
                              void* d_out, int out_size, void* d_ws, size_t ws_size,
                              hipStream_t stream) {
  const float* h       = (const float*)d_in[0];
  const int*   y       = (const int*)d_in[1];
  const float* centers = (const float*)d_in[2];
  float* out = (float*)d_out;
  float* ws  = (float*)d_ws;

  unsigned* ctr          = (unsigned*)ws;
  float*    part_reg_sum = ws + 16;
  float*    part_loss    = ws + 64;

  hipMemsetAsync(ctr, 0, 64, stream);  // reset counter each call (graph-safe)
  main_kernel<<<GRID, 256, 0, stream>>>(h, y, centers, ctr, part_loss,
                                        part_reg_sum, out);
}

// Round 15
// 27.731 us; speedup vs baseline: 1.2263x; 1.2263x over previous
//
#include <hip/hip_runtime.h>
#include <math.h>

typedef __attribute__((ext_vector_type(8))) short short8;   // 8 bf16 vals
typedef __attribute__((ext_vector_type(4))) float f32x4;

// Problem constants (fixed by the reference)
constexpr int B = 8192;
constexpr int D = 128;
constexpr int K = 256;
constexpr int RB = K / 16;      // 16 reg-blocks (C.C^T tiles), run first
constexpr int HB = B / 16;      // 512 h-blocks
constexpr int GRID = RB + HB;   // 528

// ws layout (floats):
//   ctr          : [0]   (unsigned; NEVER reset — finisher fires on old%GRID==GRID-1)
//   part_reg_sum : [16, 32)
//   part_loss    : [64, 576)

__device__ __forceinline__ short8 cvt8(float4 f0, float4 f1, float& sq) {
  sq = fmaf(f0.x, f0.x, fmaf(f0.y, f0.y, fmaf(f0.z, f0.z, fmaf(f0.w, f0.w, sq))));
  sq = fmaf(f1.x, f1.x, fmaf(f1.y, f1.y, fmaf(f1.z, f1.z, fmaf(f1.w, f1.w, sq))));
  union { short8 s; __bf16 b[8]; } u;
  u.b[0] = (__bf16)f0.x; u.b[1] = (__bf16)f0.y;
  u.b[2] = (__bf16)f0.z; u.b[3] = (__bf16)f0.w;
  u.b[4] = (__bf16)f1.x; u.b[5] = (__bf16)f1.y;
  u.b[6] = (__bf16)f1.z; u.b[7] = (__bf16)f1.w;
  return u.s;
}

// --- Single fused kernel, single graph node --------------------------------
// Blocks [0,16): reg tiles — A = centers rows, epilogue = min/−log/sum.
// Blocks [16,528): h tiles — A = h rows, epilogue = exp-sum/logsumexp/y-gather.
// A and B both loaded fp32 (L2-hot for B), converted to bf16 in-register;
// exact fp32 row/col norms via shfl (+bpermute for rows).
// C-map (m89, rounds 6/10/11-verified): col = lane&15, row = (lane>>4)*4+reg.
// Last block per call (mod-GRID atomic counter — exactly one firing per call
// for ANY counter start value, so no reset/memset node needed) reduces.
__global__ __launch_bounds__(256) void main_kernel(
    const float* __restrict__ h, const int* __restrict__ y,
    const float* __restrict__ centers,
    unsigned* ctr, float* part_loss, float* part_reg_sum,
    float* out) {
  const int t = threadIdx.x;
  const int w = t >> 6;
  const int l = t & 63;
  const int lr = l & 15;
  const int lg = l >> 4;
  const bool isreg = (blockIdx.x < RB);
  const int r0 = (isreg ? (int)blockIdx.x : (int)blockIdx.x - RB) * 16;
  const float* Ap = (isreg ? centers : h) + (size_t)(r0 + lr) * D + lg * 8;
  const int n0 = w * 64;

  // ---- A fragments + exact fp32 row norms ----
  short8 a[4];
  float sq = 0.f;
#pragma unroll
  for (int c = 0; c < 4; ++c) {
    const float4* p = reinterpret_cast<const float4*>(Ap + c * 32);
    a[c] = cvt8(p[0], p[1], sq);
  }
  sq += __shfl_xor(sq, 16);
  sq += __shfl_xor(sq, 32);
  float rr[4];  // row norm of rows r0 + lg*4 + j
#pragma unroll
  for (int j = 0; j < 4; ++j)
    rr[j] = __int_as_float(
        __builtin_amdgcn_ds_bpermute((lg * 4 + j) << 2, __float_as_int(sq)));

  // ---- B stream: fp32 load -> bf16 frag -> MFMA; fp32 col norms ----
  f32x4 zero = {0.f, 0.f, 0.f, 0.f};
  f32x4 acc[4] = {zero, zero, zero, zero};
  float cs[4] = {0.f, 0.f, 0.f, 0.f};
#pragma unroll
  for (int c = 0; c < 4; ++c) {
#pragma unroll
    for (int n = 0; n < 4; ++n) {
      const float4* p = reinterpret_cast<const float4*>(
          centers + (size_t)(n0 + n * 16 + lr) * D + c * 32 + lg * 8);
      short8 bfrag = cvt8(p[0], p[1], cs[n]);
      acc[n] = __builtin_amdgcn_mfma_f32_16x16x32_bf16(a[c], bfrag, acc[n], 0, 0, 0);
    }
  }
#pragma unroll
  for (int n = 0; n < 4; ++n) {
    cs[n] += __shfl_xor(cs[n], 16);
    cs[n] += __shfl_xor(cs[n], 32);
  }

  __shared__ float ls[4][16];
  __shared__ float ldy[4][16];
  __shared__ int s_last;

  if (!isreg) {
    int y_r[4];
#pragma unroll
    for (int j = 0; j < 4; ++j) y_r[j] = y[r0 + lg * 4 + j];
    float s[4] = {0.f, 0.f, 0.f, 0.f}, dyv[4] = {0.f, 0.f, 0.f, 0.f};
#pragma unroll
    for (int n = 0; n < 4; ++n) {
      const int colg = n0 + n * 16 + lr;
      const float ccv = cs[n];
#pragma unroll
      for (int j = 0; j < 4; ++j) {
        float dist = fmaxf(fmaf(-2.f, acc[n][j], rr[j] + ccv), 0.f);
        if (y_r[j] == colg) dyv[j] = dist;
        s[j] += __expf(-sqrtf(dist));
      }
    }
#pragma unroll
    for (int j = 0; j < 4; ++j) {
#pragma unroll
      for (int off = 1; off < 16; off <<= 1) {
        s[j]   += __shfl_xor(s[j], off);
        dyv[j] += __shfl_xor(dyv[j], off);
      }
    }
    if (lr == 0) {
#pragma unroll
      for (int j = 0; j < 4; ++j) {
        ls[w][lg * 4 + j]  = s[j];
        ldy[w][lg * 4 + j] = dyv[j];
      }
    }
    __syncthreads();
    if (t < 16) {
      float stot = (ls[0][t] + ls[1][t]) + (ls[2][t] + ls[3][t]);
      float dtot = (ldy[0][t] + ldy[1][t]) + (ldy[2][t] + ldy[3][t]);
      float v = dtot + logf(fmaxf(stot, 1e-37f));
#pragma unroll
      for (int off = 1; off < 16; off <<= 1) v += __shfl_xor(v, off);
      if (t == 0) part_loss[blockIdx.x - RB] = v;
    }
  } else {
    float pmin[4] = {INFINITY, INFINITY, INFINITY, INFINITY};
#pragma unroll
    for (int n = 0; n < 4; ++n) {
      const int colg = n0 + n * 16 + lr;
      const float ccv = cs[n];
#pragma unroll
      for (int j = 0; j < 4; ++j) {
        const int irow = r0 + lg * 4 + j;
        float pd = fmaf(-2.f, acc[n][j], rr[j] + ccv);
        if (colg != irow) pmin[j] = fminf(pmin[j], pd);
      }
    }
#pragma unroll
    for (int j = 0; j < 4; ++j) {
#pragma unroll
      for (int off = 1; off < 16; off <<= 1)
        pmin[j] = fminf(pmin[j], __shfl_xor(pmin[j], off));
    }
    if (lr == 0) {
#pragma unroll
      for (int j = 0; j < 4; ++j) ls[w][lg * 4 + j] = pmin[j];
    }
    __syncthreads();
    if (t < 16) {
      float m = fminf(fminf(ls[0][t], ls[1][t]), fminf(ls[2][t], ls[3][t]));
      float v = -logf(fmaxf(m, 1e-37f));
#pragma unroll
      for (int off = 1; off < 16; off <<= 1) v += __shfl_xor(v, off);
      if (t == 0) part_reg_sum[blockIdx.x] = v;
    }
  }

  // ---- last-block-per-call final reduction (mod-GRID counter, no reset) ----
  if (t == 0) {
    __threadfence();                       // release: partials visible device-wide
    unsigned old = atomicAdd(ctr, 1u);     // device-scope RMW (m20)
    s_last = ((old % (unsigned)GRID) == (unsigned)(GRID - 1));
  }
  __syncthreads();
  if (s_last) {
    __threadfence();                       // acquire: see all partials
    float v = (part_loss[t] + part_loss[t + 256]) * (1.0f / (float)B);
    if (t < RB) v += part_reg_sum[t];
#pragma unroll
    for (int off = 32; off; off >>= 1) v += __shfl_xor(v, off);
    __shared__ float red[4];
    if (l == 0) red[w] = v;
    __syncthreads();
    if (t == 0) out[0] = (red[0] + red[1]) + (red[2] + red[3]);
  }
}

extern "C" void kernel_launch(void* const* d_in, const int* in_sizes, int n_in,
                              void* d_out, int out_size, void* d_ws, size_t ws_size,
                              hipStream_t stream) {
  const float* h       = (const float*)d_in[0];
  const int*   y       = (const int*)d_in[1];
  const float* centers = (const float*)d_in[2];
  float* out = (float*)d_out;
  float* ws  = (float*)d_ws;

  unsigned* ctr          = (unsigned*)ws;
  float*    part_reg_sum = ws + 16;
  float*    part_loss    = ws + 64;

  main_kernel<<<GRID, 256, 0, stream>>>(h, y, centers, ctr, part_loss,
                                        part_reg_sum, out);
}

// Round 16
// 21.819 us; speedup vs baseline: 1.5585x; 1.2709x over previous
//
#include <hip/hip_runtime.h>
#include <math.h>

typedef __attribute__((ext_vector_type(8))) short short8;   // 8 bf16 vals
typedef __attribute__((ext_vector_type(4))) float f32x4;

// Problem constants (fixed by the reference)
constexpr int B = 8192;
constexpr int D = 128;
constexpr int K = 256;
constexpr int HB = B / 16;      // 512 h-blocks in main

// ws layout (floats):
//   cc           : [0, 256)
//   part_reg_sum : [256, 272)
//   part_loss    : [512, 1024)
//   cbu (bf16)   : [1024, 1024+16384)   (64 KB as bf16[256][128])

__device__ __forceinline__ short8 cvt8(float4 f0, float4 f1, float& sq) {
  sq = fmaf(f0.x, f0.x, fmaf(f0.y, f0.y, fmaf(f0.z, f0.z, fmaf(f0.w, f0.w, sq))));
  sq = fmaf(f1.x, f1.x, fmaf(f1.y, f1.y, fmaf(f1.z, f1.z, fmaf(f1.w, f1.w, sq))));
  union { short8 s; __bf16 b[8]; } u;
  u.b[0] = (__bf16)f0.x; u.b[1] = (__bf16)f0.y;
  u.b[2] = (__bf16)f0.z; u.b[3] = (__bf16)f0.w;
  u.b[4] = (__bf16)f1.x; u.b[5] = (__bf16)f1.y;
  u.b[6] = (__bf16)f1.z; u.b[7] = (__bf16)f1.w;
  return u.s;
}

// --- Kernel 1: prep — 16 cvt blocks + 16 MFMA reg-tile blocks --------------
// Blocks [0,16): centers -> bf16 cbu (row-major) + fp32 col norms cc.
// Blocks [16,32): reg tiles via MFMA — A = centers rows r0..r0+15, B = all
// 256 centers (fp32 load + in-register cvt, inline col norms). Epilogue:
// mask diagonal, min over cols, -log, sum -> part_reg_sum[tile].
__global__ __launch_bounds__(256) void prep_kernel(
    const float* __restrict__ centers, short8* __restrict__ cbu,
    float* __restrict__ cc, float* __restrict__ part_reg_sum) {
  const int t = threadIdx.x;
  if (blockIdx.x < 16) {
    const int ci = blockIdx.x;                // 16 rows each
    const int base = ci * 2048 + t * 8;       // fp32 element index
    const float4* p = reinterpret_cast<const float4*>(centers + base);
    float sq = 0.f;
    short8 o = cvt8(p[0], p[1], sq);
    cbu[ci * 256 + t] = o;
#pragma unroll
    for (int off = 1; off < 16; off <<= 1) sq += __shfl_xor(sq, off);
    if ((t & 15) == 0) cc[base / 128] = sq;   // one row per 16 threads
    return;
  }

  // ---- MFMA reg tile (verified R10/R15 isreg path) ----
  const int w = t >> 6;
  const int l = t & 63;
  const int lr = l & 15;
  const int lg = l >> 4;
  const int r0 = ((int)blockIdx.x - 16) * 16;
  const float* Ap = centers + (size_t)(r0 + lr) * D + lg * 8;
  const int n0 = w * 64;

  short8 a[4];
  float sq = 0.f;
#pragma unroll
  for (int c = 0; c < 4; ++c) {
    const float4* p = reinterpret_cast<const float4*>(Ap + c * 32);
    a[c] = cvt8(p[0], p[1], sq);
  }
  sq += __shfl_xor(sq, 16);
  sq += __shfl_xor(sq, 32);
  float rr[4];
#pragma unroll
  for (int j = 0; j < 4; ++j)
    rr[j] = __int_as_float(
        __builtin_amdgcn_ds_bpermute((lg * 4 + j) << 2, __float_as_int(sq)));

  f32x4 zero = {0.f, 0.f, 0.f, 0.f};
  f32x4 acc[4] = {zero, zero, zero, zero};
  float cs[4] = {0.f, 0.f, 0.f, 0.f};
#pragma unroll
  for (int c = 0; c < 4; ++c) {
#pragma unroll
    for (int n = 0; n < 4; ++n) {
      const float4* p = reinterpret_cast<const float4*>(
          centers + (size_t)(n0 + n * 16 + lr) * D + c * 32 + lg * 8);
      short8 bfrag = cvt8(p[0], p[1], cs[n]);
      acc[n] = __builtin_amdgcn_mfma_f32_16x16x32_bf16(a[c], bfrag, acc[n], 0, 0, 0);
    }
  }
#pragma unroll
  for (int n = 0; n < 4; ++n) {
    cs[n] += __shfl_xor(cs[n], 16);
    cs[n] += __shfl_xor(cs[n], 32);
  }

  float pmin[4] = {INFINITY, INFINITY, INFINITY, INFINITY};
#pragma unroll
  for (int n = 0; n < 4; ++n) {
    const int colg = n0 + n * 16 + lr;
    const float ccv = cs[n];
#pragma unroll
    for (int j = 0; j < 4; ++j) {
      const int irow = r0 + lg * 4 + j;
      float pd = fmaf(-2.f, acc[n][j], rr[j] + ccv);
      if (colg != irow) pmin[j] = fminf(pmin[j], pd);
    }
  }
#pragma unroll
  for (int j = 0; j < 4; ++j)
#pragma unroll
    for (int off = 1; off < 16; off <<= 1)
      pmin[j] = fminf(pmin[j], __shfl_xor(pmin[j], off));

  __shared__ float ls[4][16];
  if (lr == 0) {
#pragma unroll
    for (int j = 0; j < 4; ++j) ls[w][lg * 4 + j] = pmin[j];
  }
  __syncthreads();
  if (t < 16) {
    float m = fminf(fminf(ls[0][t], ls[1][t]), fminf(ls[2][t], ls[3][t]));
    float v = -logf(fmaxf(m, 1e-37f));
#pragma unroll
    for (int off = 1; off < 16; off <<= 1) v += __shfl_xor(v, off);
    if (t == 0) part_reg_sum[blockIdx.x - 16] = v;
  }
}

// --- Kernel 2: main — MFMA h-tiles, B from cbu (R6-verified) ---------------
// Block = 16 h rows x 256 cols, 4 waves x 64 cols. A from h fp32 (cvt in-reg,
// exact fp32 row norms via shfl+bpermute); B frags straight from cbu; col
// norms from cc. C-map (m89): col = lane&15, row = (lane>>4)*4 + reg.
__global__ __launch_bounds__(256) void main_kernel(
    const float* __restrict__ h, const int* __restrict__ y,
    const short8* __restrict__ cbu, const float* __restrict__ cc,
    float* __restrict__ part_loss) {
  const int t = threadIdx.x;
  const int w = t >> 6;
  const int l = t & 63;
  const int lr = l & 15;
  const int lg = l >> 4;
  const int r0 = blockIdx.x * 16;
  const int n0 = w * 64;

  short8 a[4];
  float sq = 0.f;
  const float* Ap = h + (size_t)(r0 + lr) * D + lg * 8;
#pragma unroll
  for (int c = 0; c < 4; ++c) {
    const float4* p = reinterpret_cast<const float4*>(Ap + c * 32);
    a[c] = cvt8(p[0], p[1], sq);
  }
  sq += __shfl_xor(sq, 16);
  sq += __shfl_xor(sq, 32);
  float rr[4];
  int y_r[4];
#pragma unroll
  for (int j = 0; j < 4; ++j) {
    rr[j] = __int_as_float(
        __builtin_amdgcn_ds_bpermute((lg * 4 + j) << 2, __float_as_int(sq)));
    y_r[j] = y[r0 + lg * 4 + j];
  }

  f32x4 zero = {0.f, 0.f, 0.f, 0.f};
  f32x4 acc[4] = {zero, zero, zero, zero};
#pragma unroll
  for (int c = 0; c < 4; ++c) {
#pragma unroll
    for (int n = 0; n < 4; ++n) {
      short8 bfrag = cbu[(size_t)(n0 + n * 16 + lr) * (D / 8) + c * 4 + lg];
      acc[n] = __builtin_amdgcn_mfma_f32_16x16x32_bf16(a[c], bfrag, acc[n], 0, 0, 0);
    }
  }

  float s[4] = {0.f, 0.f, 0.f, 0.f}, dyv[4] = {0.f, 0.f, 0.f, 0.f};
#pragma unroll
  for (int n = 0; n < 4; ++n) {
    const int colg = n0 + n * 16 + lr;
    const float ccv = cc[colg];
#pragma unroll
    for (int j = 0; j < 4; ++j) {
      float dist = fmaxf(fmaf(-2.f, acc[n][j], rr[j] + ccv), 0.f);
      if (y_r[j] == colg) dyv[j] = dist;
      s[j] += __expf(-sqrtf(dist));
    }
  }
#pragma unroll
  for (int j = 0; j < 4; ++j) {
#pragma unroll
    for (int off = 1; off < 16; off <<= 1) {
      s[j]   += __shfl_xor(s[j], off);
      dyv[j] += __shfl_xor(dyv[j], off);
    }
  }
  __shared__ float ls[4][16];
  __shared__ float ldy[4][16];
  if (lr == 0) {
#pragma unroll
    for (int j = 0; j < 4; ++j) {
      ls[w][lg * 4 + j]  = s[j];
      ldy[w][lg * 4 + j] = dyv[j];
    }
  }
  __syncthreads();
  if (t < 16) {
    float stot = (ls[0][t] + ls[1][t]) + (ls[2][t] + ls[3][t]);
    float dtot = (ldy[0][t] + ldy[1][t]) + (ldy[2][t] + ldy[3][t]);
    float v = dtot + logf(fmaxf(stot, 1e-37f));
#pragma unroll
    for (int off = 1; off < 16; off <<= 1) v += __shfl_xor(v, off);
    if (t == 0) part_loss[blockIdx.x] = v;
  }
}

// --- Kernel 3: final deterministic reduction -------------------------------
__global__ __launch_bounds__(256) void final_kernel(
    const float* __restrict__ part_loss, const float* __restrict__ part_reg_sum,
    float* __restrict__ out) {
  const int t = threadIdx.x;
  float v = (part_loss[t] + part_loss[t + 256]) * (1.0f / (float)B);
  if (t < 16) v += part_reg_sum[t];
  const int lane = t & 63;
  const int wid  = t >> 6;
#pragma unroll
  for (int off = 32; off; off >>= 1) v += __shfl_xor(v, off);
  __shared__ float red[4];
  if (lane == 0) red[wid] = v;
  __syncthreads();
  if (t == 0) out[0] = (red[0] + red[1]) + (red[2] + red[3]);
}

extern "C" void kernel_launch(void* const* d_in, const int* in_sizes, int n_in,
                              void* d_out, int out_size, void* d_ws, size_t ws_size,
                              hipStream_t stream) {
  const float* h       = (const float*)d_in[0];
  const int*   y       = (const int*)d_in[1];
  const float* centers = (const float*)d_in[2];
  float* out = (float*)d_out;
  float* ws  = (float*)d_ws;

  float*  cc           = ws;
  float*  part_reg_sum = ws + 256;
  float*  part_loss    = ws + 512;
  short8* cbu          = reinterpret_cast<short8*>(ws + 1024);

  prep_kernel<<<32, 256, 0, stream>>>(centers, cbu, cc, part_reg_sum);
  main_kernel<<<HB, 256, 0, stream>>>(h, y, cbu, cc, part_loss);
  final_kernel<<<1, 256, 0, stream>>>(part_loss, part_reg_sum, out);
}

// Round 18
// 20.177 us; speedup vs baseline: 1.6854x; 1.0814x over previous
//
#include <hip/hip_runtime.h>
#include <math.h>

typedef __attribute__((ext_vector_type(8))) short short8;   // 8 bf16 vals
typedef __attribute__((ext_vector_type(4))) float f32x4;

// Problem constants (fixed by the reference)
constexpr int B = 8192;
constexpr int D = 128;
constexpr int K = 256;
constexpr int MB = B / 16;   // 512 main blocks, 16 rows each

// ws layout (floats)
//   part_reg  : [0, 256)
//   cc        : [256, 512)
//   part_loss : [512, 1024)
//   c_bf16    : [1024, 1024+4096)   (32 KB as bf16[256][128])

__device__ __forceinline__ short8 cvt8(float4 f0, float4 f1, float& sq) {
  sq = fmaf(f0.x, f0.x, fmaf(f0.y, f0.y, fmaf(f0.z, f0.z, fmaf(f0.w, f0.w, sq))));
  sq = fmaf(f1.x, f1.x, fmaf(f1.y, f1.y, fmaf(f1.z, f1.z, fmaf(f1.w, f1.w, sq))));
  union { short8 s; __bf16 b[8]; } u;
  u.b[0] = (__bf16)f0.x; u.b[1] = (__bf16)f0.y;
  u.b[2] = (__bf16)f0.z; u.b[3] = (__bf16)f0.w;
  u.b[4] = (__bf16)f1.x; u.b[5] = (__bf16)f1.y;
  u.b[6] = (__bf16)f1.z; u.b[7] = (__bf16)f1.w;
  return u.s;
}

// --- Kernel 1: prep — reg term (blocks 0..K) + c->bf16 + cc (blocks K..K+15)
__global__ __launch_bounds__(256) void prep_kernel(const float* __restrict__ centers,
                                                   float* __restrict__ part_reg,
                                                   float* __restrict__ cc,
                                                   short8* __restrict__ cbu) {
  __shared__ float red[4];
  const int lane = threadIdx.x & 63;
  const int wid  = threadIdx.x >> 6;
  if (blockIdx.x < K) {
    // part_reg[i] = -log(min_{j!=i} ||c_i - c_j||^2)  (fp32 exact)
    const int i = blockIdx.x;
    const int j = threadIdx.x;
    const float* ci = centers + (size_t)i * D;
    const float* cj = centers + (size_t)j * D;
    float pd = 0.f;
#pragma unroll
    for (int q = 0; q < D / 4; ++q) {
      float4 a  = reinterpret_cast<const float4*>(ci)[q];
      float4 bq = reinterpret_cast<const float4*>(cj)[q];
      float dx = a.x - bq.x, dy = a.y - bq.y, dz = a.z - bq.z, dw = a.w - bq.w;
      pd = fmaf(dx, dx, fmaf(dy, dy, fmaf(dz, dz, fmaf(dw, dw, pd))));
    }
    if (j == i) pd = INFINITY;
#pragma unroll
    for (int off = 32; off; off >>= 1) pd = fminf(pd, __shfl_xor(pd, off));
    if (lane == 0) red[wid] = pd;
    __syncthreads();
    if (threadIdx.x == 0) {
      float m = fminf(fminf(red[0], red[1]), fminf(red[2], red[3]));
      part_reg[i] = -logf(m);
    }
  } else {
    // centers -> bf16 (row-major [256][128]) + cc[k] = ||c_k||^2 in fp32
    const int ci = blockIdx.x - K;            // 0..15, 16 rows each
    const int t = threadIdx.x;
    const int base = ci * 2048 + t * 8;       // fp32 element index
    const float4* p = reinterpret_cast<const float4*>(centers + base);
    float sq = 0.f;
    short8 o = cvt8(p[0], p[1], sq);
    cbu[ci * 256 + t] = o;
#pragma unroll
    for (int off = 1; off < 16; off <<= 1) sq += __shfl_xor(sq, off);
    if ((t & 15) == 0) cc[base / 128] = sq;
  }
}

// --- Kernel 2: main — MFMA bf16, block = 16 rows x 256 cols, 4 waves -------
// Wave w owns cols [w*64, w*64+64). A-frag: h rows (fp32->bf16 in-kernel,
// hh as fp32 byproduct). B-frag: c_bf16 rows (B^T pattern). C-map (m89):
// col = lane&15, row = (lane>>4)*4 + reg.
__global__ __launch_bounds__(256) void main_kernel(
    const float* __restrict__ h, const int* __restrict__ y,
    const short8* __restrict__ cbu, const float* __restrict__ cc,
    float* __restrict__ part_loss) {
  const int t = threadIdx.x;
  const int w = t >> 6;
  const int l = t & 63;
  const int lr = l & 15;   // A row / C col (in-tile)
  const int lg = l >> 4;   // k-group / C row-group
  const int r0 = blockIdx.x * 16;
  const int n0 = w * 64;

  // ---- A fragments (4 k-chunks) + hh from the same fp32 values ----
  const float* hrow = h + (size_t)(r0 + lr) * D + lg * 8;
  short8 a[4];
  float sq = 0.f;
#pragma unroll
  for (int c = 0; c < 4; ++c) {
    const float4* hp = reinterpret_cast<const float4*>(hrow + c * 32);
    a[c] = cvt8(hp[0], hp[1], sq);
  }
  // lanes {lr, lr+16, lr+32, lr+48} hold k-partials of row r0+lr -> combine
  sq += __shfl_xor(sq, 16);
  sq += __shfl_xor(sq, 32);
  // redistribute: this lane needs hh of rows r0 + lg*4 + j (held at lane lg*4+j)
  float hh_r[4];
  int y_r[4];
#pragma unroll
  for (int j = 0; j < 4; ++j) {
    hh_r[j] = __int_as_float(
        __builtin_amdgcn_ds_bpermute((lg * 4 + j) << 2, __float_as_int(sq)));
    y_r[j] = y[r0 + lg * 4 + j];
  }

  // ---- MFMA: 4 col-tiles x 4 k-chunks ----
  f32x4 zero = {0.f, 0.f, 0.f, 0.f};
  f32x4 acc[4] = {zero, zero, zero, zero};
#pragma unroll
  for (int c = 0; c < 4; ++c) {
    short8 bb[4];
#pragma unroll
    for (int n = 0; n < 4; ++n)
      bb[n] = cbu[(size_t)(n0 + n * 16 + lr) * (D / 8) + c * 4 + lg];
#pragma unroll
    for (int n = 0; n < 4; ++n)
      acc[n] = __builtin_amdgcn_mfma_f32_16x16x32_bf16(a[c], bb[n], acc[n], 0, 0, 0);
  }

  // ---- epilogue: dist, exp, y-gather, row reductions ----
  float s[4] = {0.f, 0.f, 0.f, 0.f};
  float dyv[4] = {0.f, 0.f, 0.f, 0.f};
#pragma unroll
  for (int n = 0; n < 4; ++n) {
    const int colg = n0 + n * 16 + lr;
    const float ccv = cc[colg];
#pragma unroll
    for (int j = 0; j < 4; ++j) {
      float dist = fmaxf(fmaf(-2.f, acc[n][j], hh_r[j] + ccv), 0.f);
      if (y_r[j] == colg) dyv[j] = dist;
      s[j] += __expf(-sqrtf(dist));
    }
  }
  // reduce across the 16 lanes covering each row's cols
#pragma unroll
  for (int j = 0; j < 4; ++j) {
#pragma unroll
    for (int off = 1; off < 16; off <<= 1) {
      s[j] += __shfl_xor(s[j], off);
      dyv[j] += __shfl_xor(dyv[j], off);
    }
  }
  __shared__ float ls[4][16];
  __shared__ float ldy[4][16];
  if (lr == 0) {
#pragma unroll
    for (int j = 0; j < 4; ++j) {
      ls[w][lg * 4 + j] = s[j];
      ldy[w][lg * 4 + j] = dyv[j];
    }
  }
  __syncthreads();
  if (t < 16) {
    float stot = (ls[0][t] + ls[1][t]) + (ls[2][t] + ls[3][t]);
    float dtot = (ldy[0][t] + ldy[1][t]) + (ldy[2][t] + ldy[3][t]);
    float v = dtot + logf(stot);
#pragma unroll
    for (int off = 1; off < 16; off <<= 1) v += __shfl_xor(v, off);
    if (t == 0) part_loss[blockIdx.x] = v;
  }
}

// --- Kernel 3: final deterministic reduction -------------------------------
__global__ __launch_bounds__(256) void final_kernel(
    const float* __restrict__ part_loss, const float* __restrict__ part_reg,
    float* __restrict__ out) {
  const int t = threadIdx.x;
  float v = part_reg[t] + (part_loss[t] + part_loss[t + 256]) * (1.0f / (float)B);
  const int lane = t & 63;
  const int wid  = t >> 6;
#pragma unroll
  for (int off = 32; off; off >>= 1) v += __shfl_xor(v, off);
  __shared__ float red[4];
  if (lane == 0) red[wid] = v;
  __syncthreads();
  if (t == 0) out[0] = red[0] + red[1] + red[2] + red[3];
}

extern "C" void kernel_launch(void* const* d_in, const int* in_sizes, int n_in,
                              void* d_out, int out_size, void* d_ws, size_t ws_size,
                              hipStream_t stream) {
  const float* h       = (const float*)d_in[0];
  const int*   y       = (const int*)d_in[1];
  const float* centers = (const float*)d_in[2];
  float* out = (float*)d_out;
  float* ws  = (float*)d_ws;

  float*  part_reg  = ws;
  float*  cc        = ws + 256;
  float*  part_loss = ws + 512;
  short8* cbu       = reinterpret_cast<short8*>(ws + 1024);

  prep_kernel<<<K + 16, 256, 0, stream>>>(centers, part_reg, cc, cbu);
  main_kernel<<<MB, 256, 0, stream>>>(h, y, cbu, cc, part_loss);
  final_kernel<<<1, 256, 0, stream>>>(part_loss, part_reg, out);
}